// Round 18
// baseline (138.570 us; speedup 1.0000x reference)
//
#include <hip/hip_runtime.h>
#include <math.h>

// DynamicElementAggregator: B=2, N=1024, M=1024, D=768, F=384, H=72
#define B_ 2
#define N_ 1024
#define M_ 1024
#define D_ 768
#define F_ 384
#define H_ 72
#define ROWS 8      // rows per block
#define PFH 6       // heads prefetched into LDS (as bf16) during MLP phase

typedef float f32x4 __attribute__((ext_vector_type(4)));
typedef unsigned short u16x4 __attribute__((ext_vector_type(4)));

// ---- Fully fused, wave-specialized (R17 base + deep pipelines):
//   threads 0..191 (3 waves): layer-1, 2 hidden cols each
//   threads 192..511 (5 waves): stream heads 0..5 into LDS as bf16 (96 KB),
//                               19-deep explicit load batches (~97 KB/CU)
// then all 512: layer-2 -> rwv, then slab combine (16 KB spans, NT,
//   h-loop unroll 4 -> 16 loads in flight/thread, ~128 KB/CU).
// 256 blocks x 512 threads, 8 rows/block, 1 block/CU (134.75 KB LDS).
__global__ __launch_bounds__(512) void fused_kernel(
    const float* __restrict__ x, const float* __restrict__ scores,
    const float* __restrict__ W1, const float* __restrict__ b1,
    const float* __restrict__ W2, const float* __restrict__ b2,
    const float* __restrict__ bias, float* __restrict__ out)
{
    const int t = threadIdx.x;            // 0..511
    const int blk = blockIdx.x;           // 0..255
    const int b = blk >> 7;
    const int n0 = (blk & 127) * ROWS;
    const int row0 = (b << 10) + n0;      // global flattened row

    __shared__ float xs[ROWS][D_];            // 24 KB
    __shared__ float hs[ROWS][F_ + 8];        // 12.25 KB (pitch 392)
    __shared__ float rwv[ROWS][80];           // 2.5 KB
    __shared__ unsigned short pf16[PFH][ROWS][M_];  // 96 KB (bf16 scores)

    const f32x4* __restrict__ sp = reinterpret_cast<const f32x4*>(scores);
    const int hstr = N_ * (M_ / 4);           // float4 per head panel
    const int sbase = ((b * H_) * N_ + n0) * (M_ / 4);  // (b, h=0, n0, 0)

    // ---- phase 0: stage x rows into LDS (1536 float4 / 512 threads) ----
    {
        const f32x4* xg = reinterpret_cast<const f32x4*>(x + row0 * D_);
        f32x4* xl = reinterpret_cast<f32x4*>(&xs[0][0]);
#pragma unroll
        for (int i = 0; i < 3; ++i)
            xl[t + i * 512] = xg[t + i * 512];
    }
    __syncthreads();   // b0: xs ready

    // ---- phase 1: layer-1 (t<192, 2 cols) || bf16 prefetch (t>=192) ----
    if (t < 192) {
        const int f = t;                  // cols f and f+192
        float acc0[ROWS], acc1[ROWS];
#pragma unroll
        for (int r = 0; r < ROWS; ++r) { acc0[r] = 0.0f; acc1[r] = 0.0f; }

#pragma unroll 4
        for (int d = 0; d < D_; d += 4) {
            float wa[4], wb[4];
#pragma unroll
            for (int i = 0; i < 4; ++i) {
                wa[i] = W1[(d + i) * F_ + f];
                wb[i] = W1[(d + i) * F_ + f + 192];
            }
#pragma unroll
            for (int r = 0; r < ROWS; ++r) {
                const float4 xv = *reinterpret_cast<const float4*>(&xs[r][d]);
                acc0[r] = fmaf(xv.x, wa[0], acc0[r]);
                acc0[r] = fmaf(xv.y, wa[1], acc0[r]);
                acc0[r] = fmaf(xv.z, wa[2], acc0[r]);
                acc0[r] = fmaf(xv.w, wa[3], acc0[r]);
                acc1[r] = fmaf(xv.x, wb[0], acc1[r]);
                acc1[r] = fmaf(xv.y, wb[1], acc1[r]);
                acc1[r] = fmaf(xv.z, wb[2], acc1[r]);
                acc1[r] = fmaf(xv.w, wb[3], acc1[r]);
            }
        }
        const float ba = b1[f];
        const float bb = b1[f + 192];
#pragma unroll
        for (int r = 0; r < ROWS; ++r) {
            const float v0 = acc0[r] + ba;
            const float v1 = acc1[r] + bb;
            hs[r][f]       = 0.5f * v0 * (1.0f + erff(v0 * 0.70710678118654752f));
            hs[r][f + 192] = 0.5f * v1 * (1.0f + erff(v1 * 0.70710678118654752f));
        }
    } else {
        // 320 threads stream 12288 float4 (192 KB f32) -> bf16 (96 KB LDS).
        // idx = r*320 + j, r = 0..38 (r=38 only for j<128).
        // Two 19-deep explicit batches: ~19*16B in flight per thread.
        const int j = t - 192;                // 0..319
        u16x4* pfl = reinterpret_cast<u16x4*>(&pf16[0][0][0]);
        f32x4 tmp[19];

#define PF_LOAD(U, R0)                                                   \
        {                                                                \
            const int i = (R0 + (U)) * 320 + j;                          \
            const int h = i >> 11;                                       \
            const int rem = i & 2047;                                    \
            tmp[U] = __builtin_nontemporal_load(sp + sbase + h * hstr + rem); \
        }
#define PF_STORE(U, R0)                                                  \
        {                                                                \
            const int i = (R0 + (U)) * 320 + j;                          \
            u16x4 uu;                                                    \
            _Pragma("unroll")                                            \
            for (int k = 0; k < 4; ++k)                                  \
                uu[k] = (unsigned short)((__float_as_uint(tmp[U][k]) + 0x8000u) >> 16); \
            pfl[i] = uu;                                                 \
        }
        // batch 1: r = 0..18
#pragma unroll
        for (int u = 0; u < 19; ++u) PF_LOAD(u, 0)
#pragma unroll
        for (int u = 0; u < 19; ++u) PF_STORE(u, 0)
        // batch 2: r = 19..37
#pragma unroll
        for (int u = 0; u < 19; ++u) PF_LOAD(u, 19)
#pragma unroll
        for (int u = 0; u < 19; ++u) PF_STORE(u, 19)
        // tail: r = 38, threads j < 128 only
        if (j < 128) {
            PF_LOAD(0, 38)
            PF_STORE(0, 38)
        }
#undef PF_LOAD
#undef PF_STORE
    }
    __syncthreads();   // b1: hs + pf16 ready

    // ---- phase 2: layer-2 (all 512 threads, 576 outputs) ----
#pragma unroll 1
    for (int o = t; o < ROWS * H_; o += 512) {
        const int r = o / H_;
        const int c = o - r * H_;
        float s = 0.0f;
#pragma unroll 4
        for (int k = 0; k < F_; k += 4) {
            const float4 hv = *reinterpret_cast<const float4*>(&hs[r][k]);
            s = fmaf(hv.x, W2[(k + 0) * H_ + c], s);
            s = fmaf(hv.y, W2[(k + 1) * H_ + c], s);
            s = fmaf(hv.z, W2[(k + 2) * H_ + c], s);
            s = fmaf(hv.w, W2[(k + 3) * H_ + c], s);
        }
        rwv[r][c] = s + b2[c];
    }
    __syncthreads();   // b2: rwv ready

    // ---- phase 3: combine. t -> (rows r0v..r0v+3, float4-col) ----
    const int col = t & 255;
    const int r0v = (t >> 8) * 4;             // 0 or 4

    const int base = sbase + r0v * (M_ / 4) + col;

    f32x4 a0 = 0.f, a1 = 0.f, a2 = 0.f, a3 = 0.f;
    // global heads PFH..71 (NT, 16 KB contiguous per head per block),
    // unroll 4 -> 16 NT loads in flight per thread.
#pragma unroll 4
    for (int h = PFH; h < H_; ++h) {
        const int ib = base + h * hstr;
        const f32x4 v0 = __builtin_nontemporal_load(sp + ib);
        const f32x4 v1 = __builtin_nontemporal_load(sp + ib + 256);
        const f32x4 v2 = __builtin_nontemporal_load(sp + ib + 512);
        const f32x4 v3 = __builtin_nontemporal_load(sp + ib + 768);
        const float w0 = rwv[r0v + 0][h];
        const float w1 = rwv[r0v + 1][h];
        const float w2 = rwv[r0v + 2][h];
        const float w3 = rwv[r0v + 3][h];
#pragma unroll
        for (int j = 0; j < 4; ++j) {
            a0[j] = fmaf(w0, v0[j], a0[j]);
            a1[j] = fmaf(w1, v1[j], a1[j]);
            a2[j] = fmaf(w2, v2[j], a2[j]);
            a3[j] = fmaf(w3, v3[j], a3[j]);
        }
    }
    // LDS heads 0..PFH-1 (bf16 -> f32 via <<16)
#pragma unroll
    for (int h = 0; h < PFH; ++h) {
        const u16x4 u0 = *reinterpret_cast<const u16x4*>(&pf16[h][r0v + 0][col * 4]);
        const u16x4 u1 = *reinterpret_cast<const u16x4*>(&pf16[h][r0v + 1][col * 4]);
        const u16x4 u2 = *reinterpret_cast<const u16x4*>(&pf16[h][r0v + 2][col * 4]);
        const u16x4 u3 = *reinterpret_cast<const u16x4*>(&pf16[h][r0v + 3][col * 4]);
        const float w0 = rwv[r0v + 0][h];
        const float w1 = rwv[r0v + 1][h];
        const float w2 = rwv[r0v + 2][h];
        const float w3 = rwv[r0v + 3][h];
#pragma unroll
        for (int j = 0; j < 4; ++j) {
            a0[j] = fmaf(w0, __uint_as_float((unsigned)u0[j] << 16), a0[j]);
            a1[j] = fmaf(w1, __uint_as_float((unsigned)u1[j] << 16), a1[j]);
            a2[j] = fmaf(w2, __uint_as_float((unsigned)u2[j] << 16), a2[j]);
            a3[j] = fmaf(w3, __uint_as_float((unsigned)u3[j] << 16), a3[j]);
        }
    }

    const float bv = bias[0];
#pragma unroll
    for (int j = 0; j < 4; ++j) { a0[j] += bv; a1[j] += bv; a2[j] += bv; a3[j] += bv; }

    f32x4* __restrict__ op = reinterpret_cast<f32x4*>(out);
    const int obase = (row0 + r0v) * (M_ / 4) + col;
    __builtin_nontemporal_store(a0, op + obase);
    __builtin_nontemporal_store(a1, op + obase + 256);
    __builtin_nontemporal_store(a2, op + obase + 512);
    __builtin_nontemporal_store(a3, op + obase + 768);
}

extern "C" void kernel_launch(void* const* d_in, const int* in_sizes, int n_in,
                              void* d_out, int out_size, void* d_ws, size_t ws_size,
                              hipStream_t stream) {
    const float* x      = (const float*)d_in[0];
    const float* scores = (const float*)d_in[1];
    const float* W1     = (const float*)d_in[2];
    const float* b1     = (const float*)d_in[3];
    const float* W2     = (const float*)d_in[4];
    const float* b2     = (const float*)d_in[5];
    const float* bias   = (const float*)d_in[6];
    float* out = (float*)d_out;

    fused_kernel<<<(B_ * N_) / ROWS, 512, 0, stream>>>(
        x, scores, W1, b1, W2, b2, bias, out);
}